// Round 7
// baseline (725.683 us; speedup 1.0000x reference)
//
#include <hip/hip_runtime.h>
#include <hip/hip_bf16.h>
#include <math.h>

#define HID 256

typedef __attribute__((ext_vector_type(4))) float f32x4;
typedef __attribute__((ext_vector_type(8))) _Float16 f16x8;

static __device__ __forceinline__ float f16tof(unsigned short u) {
    _Float16 h; __builtin_memcpy(&h, &u, 2); return (float)h;
}
static __device__ __forceinline__ unsigned short ftof16(float f) {
    _Float16 h = (_Float16)f; unsigned short u; __builtin_memcpy(&u, &h, 2); return u;
}

// async global->LDS, 16B per lane (dest = wave-uniform base + lane*16)
static __device__ __forceinline__ void gld16(const void* g, void* l) {
    __builtin_amdgcn_global_load_lds(
        (const __attribute__((address_space(1))) void*)g,
        (__attribute__((address_space(3))) void*)l, 16, 0, 0);
}

// ---------------------------------------------------------------- edge prep

__global__ void hist_kernel(const int* __restrict__ dst, int* __restrict__ deg, int E) {
    int e = blockIdx.x * blockDim.x + threadIdx.x;
    if (e < E) atomicAdd(&deg[dst[e]], 1);
}

__global__ __launch_bounds__(256) void scan1_kernel(const int* __restrict__ deg,
        int* __restrict__ incl, int* __restrict__ bsum, int N) {
    __shared__ int s[256];
    int i = blockIdx.x * 256 + threadIdx.x;
    int v = (i < N) ? deg[i] : 0;
    s[threadIdx.x] = v;
    __syncthreads();
#pragma unroll
    for (int off = 1; off < 256; off <<= 1) {
        int t = (threadIdx.x >= off) ? s[threadIdx.x - off] : 0;
        __syncthreads();
        s[threadIdx.x] += t;
        __syncthreads();
    }
    if (i < N) incl[i] = s[threadIdx.x];
    if (threadIdx.x == 255) bsum[blockIdx.x] = s[255];
}

__global__ __launch_bounds__(256) void scan2_kernel(int* __restrict__ bsum, int nb) {
    __shared__ int s[256];
    int v = (threadIdx.x < nb) ? bsum[threadIdx.x] : 0;
    s[threadIdx.x] = v;
    __syncthreads();
#pragma unroll
    for (int off = 1; off < 256; off <<= 1) {
        int t = (threadIdx.x >= off) ? s[threadIdx.x - off] : 0;
        __syncthreads();
        s[threadIdx.x] += t;
        __syncthreads();
    }
    if (threadIdx.x < nb) bsum[threadIdx.x] = s[threadIdx.x] - v;  // exclusive
}

__global__ __launch_bounds__(256) void scan3_kernel(const int* __restrict__ deg,
        const int* __restrict__ incl, const int* __restrict__ bsum,
        int* __restrict__ rowptr, int* __restrict__ cursor,
        float* __restrict__ dinv, int N, int E) {
    int i = blockIdx.x * 256 + threadIdx.x;
    if (i < N) {
        int d = deg[i];
        int start = bsum[blockIdx.x] + incl[i] - d;
        rowptr[i] = start;
        cursor[i] = start;
        dinv[i] = 1.0f / sqrtf((float)(d + 1));
    }
    if (i == N) rowptr[N] = E;
}

__global__ void fill_kernel(const int* __restrict__ src, const int* __restrict__ dst,
        int* __restrict__ cursor, int* __restrict__ colsrc, int E) {
    int e = blockIdx.x * blockDim.x + threadIdx.x;
    if (e < E) {
        int slot = atomicAdd(&cursor[dst[e]], 1);
        colsrc[slot] = src[e];
    }
}

// ---------------------------------------------------------------- weight prep
struct WPtrs { const float* w[8]; };

__global__ __launch_bounds__(256) void convw_kernel(WPtrs wp, _Float16* __restrict__ btf) {
    __shared__ _Float16 S[64][72];
    int mat = blockIdx.y;
    int tk = blockIdx.x >> 2, tn = blockIdx.x & 3;  // 64x64 tile
    const float* W = wp.w[mat];
    int kr = threadIdx.x >> 2, nc = (threadIdx.x & 3) * 16;
    const float* p = W + (size_t)(tk * 64 + kr) * 256 + tn * 64 + nc;
#pragma unroll
    for (int i = 0; i < 16; i++) S[nc + i][kr] = (_Float16)p[i];
    __syncthreads();
    int nr = threadIdx.x >> 2, kc = (threadIdx.x & 3) * 16;
    size_t ob = (size_t)mat * 65536 + (size_t)(tn * 64 + nr) * 256 + tk * 64 + kc;
#pragma unroll
    for (int i = 0; i < 16; i++) btf[ob + i] = S[nr][kc + i];
}

// ---------------------------------------------------------------- x -> f16
__global__ __launch_bounds__(256) void xcvt_kernel(const float* __restrict__ x,
        _Float16* __restrict__ xh, int n8) {
    int i = blockIdx.x * 256 + threadIdx.x;
    if (i < n8) {
        f32x4 a = *(const f32x4*)(x + (size_t)i * 8);
        f32x4 b = *(const f32x4*)(x + (size_t)i * 8 + 4);
        f16x8 h;
#pragma unroll
        for (int j = 0; j < 4; j++) { h[j] = (_Float16)a[j]; h[j + 4] = (_Float16)b[j]; }
        *(f16x8*)(xh + (size_t)i * 8) = h;
    }
}

// ---------------------------------------------------------------- GEMM (f16 MFMA, 2-phase dbuf)
// C[Mpad,256](f16) = act(A[Mpad,256](f16) @ W + bias); Bt[n][k] f16 transposed.
// BM=128, BN=64, BK=64; 256 thr = 4 waves (2x2), wave tile 64x32.
// Double-buffered LDS (2 x 24KB), STAGE(t+1) issued before compute(t),
// single __syncthreads per iter (T3-minimal 2-phase, m248 pattern).
// XOR-swizzle: phys 16B slot = logical ^ (row&7), both-sides (stage-src + read).

template<int ACT>
__global__ __launch_bounds__(256, 3) void gemm_kernel(
        const _Float16* __restrict__ A, const _Float16* __restrict__ Bt,
        const float* __restrict__ bias, unsigned short* __restrict__ C) {
    __shared__ __align__(16) char As[2][128 * 128];  // 16 KB each
    __shared__ __align__(16) char Bs[2][64 * 128];   //  8 KB each
    const int tid = threadIdx.x;
    const int wave = tid >> 6, lane = tid & 63;
    const int row0 = blockIdx.x * 128, col0 = blockIdx.y * 64;
    const int wm = wave >> 1, wn = wave & 1;
    const int lr = lane & 15;
    const int lsub = lane >> 3, lslot = lane & 7;  // staging: 8 lanes/row

    f32x4 acc[4][2];
#pragma unroll
    for (int m = 0; m < 4; m++)
#pragma unroll
        for (int n = 0; n < 2; n++) acc[m][n] = (f32x4)0.0f;

    // ---- stage one K-tile (A 128x64 + B 64x64) into buffer b
    auto STAGE = [&](int b, int k0) {
#pragma unroll
        for (int c6 = 0; c6 < 6; ++c6) {
            int chunk = wave * 6 + c6;  // wave-uniform
            const _Float16* gp;
            char* lp;
            if (chunk < 16) {
                int r = chunk * 8 + lsub;
                gp = A + (size_t)(row0 + r) * 256 + k0 + (lslot ^ (r & 7)) * 8;
                lp = As[b] + chunk * 1024;
            } else {
                int r = (chunk - 16) * 8 + lsub;
                gp = Bt + (size_t)(col0 + r) * 256 + k0 + (lslot ^ (r & 7)) * 8;
                lp = Bs[b] + (chunk - 16) * 1024;
            }
            gld16(gp, lp + lane * 16);
        }
    };

    STAGE(0, 0);
    __syncthreads();  // drain prologue stage

    for (int t = 0; t < 4; ++t) {
        const int cur = t & 1;
        if (t < 3) STAGE(cur ^ 1, (t + 1) * 64);  // prefetch next tile (in flight under compute)

        // ---- compute tile t from buffer cur: 2 sub-K of 32
#pragma unroll
        for (int kk = 0; kk < 2; ++kk) {
            const int kb = kk * 64 + (lane >> 4) * 16;
            f16x8 af[4], bf[2];
#pragma unroll
            for (int m = 0; m < 4; ++m) {
                int r = wm * 64 + m * 16 + lr;
                af[m] = *(const f16x8*)(As[cur] + r * 128 + (kb ^ ((r & 7) << 4)));
            }
#pragma unroll
            for (int n = 0; n < 2; ++n) {
                int r = wn * 32 + n * 16 + lr;
                bf[n] = *(const f16x8*)(Bs[cur] + r * 128 + (kb ^ ((r & 7) << 4)));
            }
#pragma unroll
            for (int m = 0; m < 4; ++m)
#pragma unroll
                for (int n = 0; n < 2; ++n)
                    acc[m][n] = __builtin_amdgcn_mfma_f32_16x16x32_f16(af[m], bf[n], acc[m][n], 0, 0, 0);
        }
        __syncthreads();  // reads of cur done + next stage drained (vmcnt0 at barrier)
    }

    // ---- epilogue: C/D layout col=lane&15, row=(lane>>4)*4+j (row-padded, no guard)
#pragma unroll
    for (int m = 0; m < 4; ++m) {
        int rb = row0 + wm * 64 + m * 16 + (lane >> 4) * 4;
#pragma unroll
        for (int n = 0; n < 2; ++n) {
            int col = col0 + wn * 32 + n * 16 + lr;
            float bv = bias ? bias[col] : 0.0f;
#pragma unroll
            for (int j = 0; j < 4; ++j) {
                float xv = acc[m][n][j] + bv;
                if (ACT) xv = xv > 0.0f ? xv : expm1f(xv);
                C[(size_t)(rb + j) * 256 + col] = ftof16(xv);
            }
        }
    }
}

// ---------------------------------------------------------------- aggregation
// h f16 [*,256]; out f16. 256 threads = 4 waves; 2 waves per node (edge-parity
// split halves the serial gather chain); partials combined via LDS.
__global__ __launch_bounds__(256) void agg_kernel(const unsigned short* __restrict__ h,
        const float* __restrict__ dinv, const int* __restrict__ rowptr,
        const int* __restrict__ colsrc, const float* __restrict__ bias,
        unsigned short* __restrict__ out, int doLN, const float* __restrict__ g,
        const float* __restrict__ lb, int N) {
    __shared__ int2 se[4][64];
    __shared__ float part[2][256];
    const int w = threadIdx.x >> 6, lane = threadIdx.x & 63;
    const int sub = w & 1;        // edge parity handled by this wave
    const int local = w >> 1;     // node slot in block
    const int node = blockIdx.x * 2 + local;
    const bool valid = node < N;
    const int j0 = lane * 4;

    float acc0 = 0.f, acc1 = 0.f, acc2 = 0.f, acc3 = 0.f;
    if (valid) {
        const float di = dinv[node];
        if (sub == 0) {  // self-loop term on parity-0 wave
            const float dd = di * di;
            uint2 us = *(const uint2*)(h + (size_t)node * 256 + j0);
            acc0 = f16tof((unsigned short)(us.x & 0xFFFF)) * dd;
            acc1 = f16tof((unsigned short)(us.x >> 16)) * dd;
            acc2 = f16tof((unsigned short)(us.y & 0xFFFF)) * dd;
            acc3 = f16tof((unsigned short)(us.y >> 16)) * dd;
        }
        const int s0 = rowptr[node], s1 = rowptr[node + 1];
        for (int base = s0 + sub; base < s1; base += 128) {
            int idx = base + lane * 2;
            int cnt = min(64, (s1 - base + 1) >> 1);
            if (idx < s1) {
                int s = colsrc[idx];
                se[w][lane] = make_int2(s, __float_as_int(dinv[s] * di));
            }
            // same-wave LDS write->read: ordered by lgkmcnt, no barrier needed
#pragma unroll 4
            for (int i = 0; i < cnt; i++) {
                int2 e = se[w][i];
                uint2 uu = *(const uint2*)(h + (size_t)e.x * 256 + j0);
                float wt = __int_as_float(e.y);
                acc0 = fmaf(f16tof((unsigned short)(uu.x & 0xFFFF)), wt, acc0);
                acc1 = fmaf(f16tof((unsigned short)(uu.x >> 16)), wt, acc1);
                acc2 = fmaf(f16tof((unsigned short)(uu.y & 0xFFFF)), wt, acc2);
                acc3 = fmaf(f16tof((unsigned short)(uu.y >> 16)), wt, acc3);
            }
        }
        if (sub == 1) *(f32x4*)&part[local][j0] = (f32x4){acc0, acc1, acc2, acc3};
    }
    __syncthreads();
    if (sub == 1 || !valid) return;

    f32x4 p = *(const f32x4*)&part[local][j0];
    acc0 += p[0]; acc1 += p[1]; acc2 += p[2]; acc3 += p[3];

    f32x4 bv = *(const f32x4*)(bias + j0);
    acc0 += bv[0]; acc1 += bv[1]; acc2 += bv[2]; acc3 += bv[3];
    acc0 = acc0 > 0.0f ? acc0 : expm1f(acc0);
    acc1 = acc1 > 0.0f ? acc1 : expm1f(acc1);
    acc2 = acc2 > 0.0f ? acc2 : expm1f(acc2);
    acc3 = acc3 > 0.0f ? acc3 : expm1f(acc3);

    if (doLN) {
        float v = acc0 + acc1 + acc2 + acc3;
#pragma unroll
        for (int off = 32; off; off >>= 1) v += __shfl_xor(v, off, 64);
        float mu = v * (1.0f / 256.0f);
        float d0 = acc0 - mu, d1 = acc1 - mu, d2 = acc2 - mu, d3 = acc3 - mu;
        float q = d0 * d0 + d1 * d1 + d2 * d2 + d3 * d3;
#pragma unroll
        for (int off = 32; off; off >>= 1) q += __shfl_xor(q, off, 64);
        float rs = rsqrtf(q * (1.0f / 256.0f) + 1e-5f);
        f32x4 gv = *(const f32x4*)(g + j0);
        f32x4 lv = *(const f32x4*)(lb + j0);
        acc0 = d0 * rs * gv[0] + lv[0];
        acc1 = d1 * rs * gv[1] + lv[1];
        acc2 = d2 * rs * gv[2] + lv[2];
        acc3 = d3 * rs * gv[3] + lv[3];
    }

    unsigned lo = (unsigned)ftof16(acc0) | ((unsigned)ftof16(acc1) << 16);
    unsigned hi = (unsigned)ftof16(acc2) | ((unsigned)ftof16(acc3) << 16);
    *(uint2*)(out + (size_t)node * 256 + j0) = make_uint2(lo, hi);
}

// ---------------------------------------------------------------- final head
__global__ __launch_bounds__(256) void final_kernel(const unsigned short* __restrict__ x,
        const float* __restrict__ W, const float* __restrict__ b,
        float* __restrict__ out, int M) {
    __shared__ float sW[256 * 25];
    for (int i = threadIdx.x; i < 256 * 25; i += 256) sW[i] = W[i];
    __syncthreads();
    int group = threadIdx.x >> 5;  // 8 nodes per block
    int c = threadIdx.x & 31;
    int node = blockIdx.x * 8 + group;
    if (node >= M || c >= 25) return;
    const uint2* xr = (const uint2*)(x + (size_t)node * 256);
    float acc = b[c];
#pragma unroll 8
    for (int k4 = 0; k4 < 64; k4++) {
        uint2 v = xr[k4];
        int k = k4 * 4;
        acc = fmaf(f16tof((unsigned short)(v.x & 0xFFFF)), sW[(k + 0) * 25 + c],
              fmaf(f16tof((unsigned short)(v.x >> 16)),   sW[(k + 1) * 25 + c],
              fmaf(f16tof((unsigned short)(v.y & 0xFFFF)), sW[(k + 2) * 25 + c],
              fmaf(f16tof((unsigned short)(v.y >> 16)),    sW[(k + 3) * 25 + c], acc))));
    }
    out[(size_t)node * 25 + c] = 1.0f / (1.0f + expf(-acc));
}

// ---------------------------------------------------------------- launch

extern "C" void kernel_launch(void* const* d_in, const int* in_sizes, int n_in,
                              void* d_out, int out_size, void* d_ws, size_t ws_size,
                              hipStream_t stream) {
    const float* x       = (const float*)d_in[0];
    const int*   ei      = (const int*)d_in[1];
    const float* W_mlp   = (const float*)d_in[2];
    const float* b_mlp   = (const float*)d_in[3];
    const float* W_conv1 = (const float*)d_in[4];
    const float* b_conv1 = (const float*)d_in[5];
    const float* W_hid   = (const float*)d_in[6];
    const float* b_hid   = (const float*)d_in[7];
    const float* ln_g    = (const float*)d_in[8];
    const float* ln_b    = (const float*)d_in[9];
    const float* W_post  = (const float*)d_in[10];
    const float* b_post  = (const float*)d_in[11];
    const float* W_lin   = (const float*)d_in[12];
    const float* b_lin   = (const float*)d_in[13];
    float* out = (float*)d_out;

    const int N = in_sizes[0] / HID;   // 50000
    const int E = in_sizes[1] / 2;     // 800000
    const int* src = ei;
    const int* dst = ei + E;
    const int NB = (N + 255) / 256;
    const int Mpad = (N + 127) & ~127; // 50048

    // workspace layout (f16 activations, padded rows)
    unsigned short* buf0 = (unsigned short*)d_ws;              // Mpad*256 f16
    unsigned short* buf1 = buf0 + (size_t)Mpad * HID;          // Mpad*256 f16
    _Float16* xh  = (_Float16*)(buf1 + (size_t)Mpad * HID);    // Mpad*256 f16
    float* dinv   = (float*)(xh + (size_t)Mpad * HID);         // N
    int*   deg    = (int*)(dinv + N);                          // N
    int*   rowptr = deg + N;                                   // N+1
    int*   cursor = rowptr + N + 1;                            // N
    int*   colsrc = cursor + N;                                // E
    int*   incl   = colsrc + E;                                // N
    int*   bsum   = incl + N;                                  // <=256
    uintptr_t bp  = ((uintptr_t)(bsum + 256) + 255) & ~(uintptr_t)255;
    _Float16* btf = (_Float16*)bp;                             // 8*65536 f16

    // ---- weight prep (8 matrices -> transposed f16 planes)
    WPtrs wp;
    wp.w[0] = W_mlp;
    wp.w[1] = W_mlp + 65536;
    wp.w[2] = W_conv1;
    wp.w[3] = W_hid;
    wp.w[4] = W_hid + 65536;
    wp.w[5] = W_hid + 2 * 65536;
    wp.w[6] = W_post;
    wp.w[7] = W_post + 65536;
    convw_kernel<<<dim3(16, 8), 256, 0, stream>>>(wp, btf);

    // ---- x -> f16
    xcvt_kernel<<<(N * HID / 8 + 255) / 256, 256, 0, stream>>>(x, xh, N * HID / 8);

    // ---- edge prep
    hipMemsetAsync(deg, 0, (size_t)N * sizeof(int), stream);
    hist_kernel<<<(E + 255) / 256, 256, 0, stream>>>(dst, deg, E);
    scan1_kernel<<<NB, 256, 0, stream>>>(deg, incl, bsum, N);
    scan2_kernel<<<1, 256, 0, stream>>>(bsum, NB);
    scan3_kernel<<<NB + 1, 256, 0, stream>>>(deg, incl, bsum, rowptr, cursor, dinv, N, E);
    fill_kernel<<<(E + 255) / 256, 256, 0, stream>>>(src, dst, cursor, colsrc, E);

    dim3 gg(Mpad / 128, 4);
    const size_t WM = 65536;
    const _Float16* f0 = (const _Float16*)buf0;
    const _Float16* f1 = (const _Float16*)buf1;
    const int nagg = (N + 1) / 2;

    // ---- pre-MLP: xh -> buf1 -> buf0 (celu)
    gemm_kernel<1><<<gg, 256, 0, stream>>>(xh, btf + 0 * WM, b_mlp,       buf1);
    gemm_kernel<1><<<gg, 256, 0, stream>>>(f1, btf + 1 * WM, b_mlp + 256, buf0);

    // ---- conv1: h = buf0@Wc -> buf1, agg -> buf0 (celu, no LN)
    gemm_kernel<0><<<gg, 256, 0, stream>>>(f0, btf + 2 * WM, nullptr, buf1);
    agg_kernel<<<nagg, 256, 0, stream>>>(buf1, dinv, rowptr, colsrc, b_conv1, buf0, 0, nullptr, nullptr, N);

    // ---- hidden convs: buf0 -> buf1 -> buf0 (celu + LN)
    for (int i = 0; i < 3; i++) {
        gemm_kernel<0><<<gg, 256, 0, stream>>>(f0, btf + (size_t)(3 + i) * WM, nullptr, buf1);
        agg_kernel<<<nagg, 256, 0, stream>>>(buf1, dinv, rowptr, colsrc, b_hid + i * 256, buf0, 1, ln_g, ln_b, N);
    }

    // ---- post-MLP: buf0 -> buf1 -> buf0 (celu)
    gemm_kernel<1><<<gg, 256, 0, stream>>>(f0, btf + 6 * WM, b_post,       buf1);
    gemm_kernel<1><<<gg, 256, 0, stream>>>(f1, btf + 7 * WM, b_post + 256, buf0);

    // ---- head + sigmoid
    final_kernel<<<(N + 7) / 8, 256, 0, stream>>>(buf0, W_lin, b_lin, out, N);
    (void)ws_size; (void)n_in; (void)out_size;
}